// Round 4
// baseline (287.566 us; speedup 1.0000x reference)
//
#include <hip/hip_runtime.h>

#define DI __device__ __forceinline__

typedef float  f32x2  __attribute__((ext_vector_type(2)));
typedef float  f32x4  __attribute__((ext_vector_type(4)));
typedef float  f32x16 __attribute__((ext_vector_type(16)));
typedef __bf16 bf16x8 __attribute__((ext_vector_type(8)));
typedef unsigned u32x2 __attribute__((ext_vector_type(2)));
typedef unsigned u32x4 __attribute__((ext_vector_type(4)));

static constexpr int TB   = 2048;   // tokens per batch
static constexpr int NTOK = 8192;   // 4 * 2048
static constexpr int EMB  = 1024;
static constexpr int FQKV = 3072;

// RTNE float -> bf16 bits
DI unsigned short f2bf(float f) {
  union { float f; unsigned u; } v; v.f = f;
  unsigned r = v.u + 0x7FFFu + ((v.u >> 16) & 1u);
  return (unsigned short)(r >> 16);
}

DI unsigned pack2bf(float a, float b) {
#if __has_builtin(__builtin_amdgcn_cvt_pk_bf16_f32)
  typedef __bf16 bf16x2 __attribute__((ext_vector_type(2)));
  bf16x2 r = __builtin_amdgcn_cvt_pk_bf16_f32(a, b);
  return __builtin_bit_cast(unsigned, r);
#else
  unsigned ua = __builtin_bit_cast(unsigned, a) + 0x8000u;
  unsigned ub = __builtin_bit_cast(unsigned, b) + 0x8000u;
  return __builtin_amdgcn_perm(ub, ua, 0x07060302u);
#endif
}

DI void plswap(unsigned& a, unsigned& b) {
#if __has_builtin(__builtin_amdgcn_permlane32_swap)
  u32x2 r = __builtin_amdgcn_permlane32_swap(a, b, false, false);
  a = r.x; b = r.y;
#else
  const bool hi = (threadIdx.x & 32) != 0;
  unsigned ax = (unsigned)__shfl_xor((int)a, 32);
  unsigned bx = (unsigned)__shfl_xor((int)b, 32);
  unsigned na = hi ? bx : a;
  unsigned nb = hi ? b : ax;
  a = na; b = nb;
#endif
}

DI bf16x8 frag4(unsigned a, unsigned b, unsigned c, unsigned d) {
  u32x4 u = {a, b, c, d};
  return __builtin_bit_cast(bf16x8, u);
}

// async global->LDS, 16B per lane; LDS dest = wave-uniform base + lane*16
DI void gload16(const void* g, void* l) {
  __builtin_amdgcn_global_load_lds(
      (__attribute__((address_space(1))) void*)(g),
      (__attribute__((address_space(3))) void*)(l), 16, 0, 0);
}

DI void wait_vm4() { asm volatile("s_waitcnt vmcnt(4)" ::: "memory"); }
DI void wait_vm0() { asm volatile("s_waitcnt vmcnt(0)" ::: "memory"); }
DI void rbar()     { __builtin_amdgcn_s_barrier(); }
DI void sfence()   { __builtin_amdgcn_sched_barrier(0); }

DI void syncdrain() {
  __builtin_amdgcn_s_waitcnt(0);
  __syncthreads();
}

// ---------------- fp32 -> bf16 conversion for x, w_qkv, w_out ----------------
__global__ __launch_bounds__(256)
void cvt_kernel(const float4* __restrict__ x, const float4* __restrict__ wq,
                const float4* __restrict__ wo,
                ushort4* __restrict__ xb, ushort4* __restrict__ wqb,
                ushort4* __restrict__ wob) {
  const int i  = blockIdx.x * 256 + threadIdx.x;
  const int nx = NTOK * EMB / 4;
  const int nq = FQKV * EMB / 4;
  float4 v; ushort4* dst;
  if (i < nx)           { v = x[i];           dst = xb  + i; }
  else if (i < nx + nq) { v = wq[i - nx];     dst = wqb + (i - nx); }
  else                  { v = wo[i - nx - nq]; dst = wob + (i - nx - nq); }
  ushort4 p;
  p.x = f2bf(v.x); p.y = f2bf(v.y); p.z = f2bf(v.z); p.w = f2bf(v.w);
  *dst = p;
}

// ---------------- 256x256 bf16 GEMM, 8-phase (4 phases/K-tile, 2 tiles deep) -
// r3: counted-vmcnt on 2-phase was null (572 TF = the m230/m233 2-phase
// structural plateau; stage+wait+barrier critical path). True fix is the
// m201-style phase schedule. Derivation (hazard-closed):
//   phases = C-quadrants (mh,nh) in order (0,0),(0,1),(1,0),(1,1).
//   LDS quarter-regions die progressively: A-mh0 after p1, B-nh0 after p2,
//   A-mh1/B-nh1 at tile end. Stage TWO tiles ahead into just-dead regions:
//     p0: stage (t+1).A1 -> other dbuf (dead since t-1 finished)
//     p1: stage (t+1).B1 -> other dbuf
//     p2: stage (t+2).A0 -> CURRENT dbuf (A-mh0 quarter died at p1's barrier)
//     p3: stage (t+2).B0 -> CURRENT dbuf (B-nh0 quarter died at p2's barrier)
//   One barrier/phase. One counted wait per tile boundary: vmcnt(4) forces
//   (FIFO) tile-(t+1)'s 4 halves landed, leaves (t+2)'s 2 halves in flight.
//   Loads are therefore waited >=4 phases (~1000cy of MFMA) after issue —
//   never drained in the main loop. Final-tile boundary uses vmcnt(0) since
//   the 2 younger prefetches don't exist there.
// A-quarter mh rows = {r : (r>>6)&1 == mh}; B-quarter nh rows = {(r>>5)&1==nh}
// (strided because wave (wm,wn) reads its own 128/64-row band each phase).
// Swizzle identical to r1/r2 (measured 0 bank conflicts): LDS granule g of
// row r holds source granule g ^ (r&7); reads XOR the same way.
template <int MODE>
__global__ __launch_bounds__(512, 2)
void gemm8p(const unsigned short* __restrict__ A,
            const unsigned short* __restrict__ Bt,
            const int K,
            unsigned short* __restrict__ qk,
            unsigned short* __restrict__ vT,
            float* __restrict__ outp) {
  __shared__ unsigned short sA[2][256 * 64];   // 32KB each
  __shared__ unsigned short sB[2][256 * 64];
  const int tid  = threadIdx.x;
  const int w    = tid >> 6;          // 0..7
  const int l    = tid & 63;
  const int quad = l >> 4;
  const int lr   = l & 15;
  // XCD-aware bijective swizzle (nwg % 8 == 0 for both grids)
  const int nwg  = gridDim.x * gridDim.y;
  const int orig = blockIdx.y * gridDim.x + blockIdx.x;
  const int swz  = (orig & 7) * (nwg >> 3) + (orig >> 3);
  const int n0   = (swz % gridDim.x) * 256;
  const int m0   = (swz / gridDim.x) * 256;
  const int wm   = (w >> 2) * 128;    // wave row offset in tile
  const int wn   = (w & 3) * 64;      // wave col offset in tile

  f32x4 acc[8][4];
#pragma unroll
  for (int i = 0; i < 8; ++i)
#pragma unroll
    for (int j = 0; j < 4; ++j) acc[i][j] = {0.f, 0.f, 0.f, 0.f};

  // ---- staging geometry ----
  const int srow8 = l >> 3;                 // 0..7
  const int gsw   = ((l & 7) ^ srow8) * 8;  // pre-swizzled source granule
  // quarter-row starts for this wave's two load slots (q0 = w*16 + jj*8)
  // A quarter mh: r = ((q0>>6)<<7) + mh*64 + (q0&63)
  // B quarter nh: r = ((q0>>5)<<6) + nh*32 + (q0&31)
  int rA[2][2], rB[2][2];
#pragma unroll
  for (int mh = 0; mh < 2; ++mh)
#pragma unroll
    for (int jj = 0; jj < 2; ++jj) {
      const int q0 = w * 16 + jj * 8;
      rA[mh][jj] = ((q0 >> 6) << 7) + mh * 64 + (q0 & 63);
      rB[mh][jj] = ((q0 >> 5) << 6) + mh * 32 + (q0 & 31);
    }
  const unsigned short* gAp[2][2];
  const unsigned short* gBp[2][2];
  int ldsA[2][2], ldsB[2][2];
#pragma unroll
  for (int mh = 0; mh < 2; ++mh)
#pragma unroll
    for (int jj = 0; jj < 2; ++jj) {
      gAp[mh][jj] = A  + (long)(m0 + rA[mh][jj] + srow8) * K + gsw;
      gBp[mh][jj] = Bt + (long)(n0 + rB[mh][jj] + srow8) * K + gsw;
      ldsA[mh][jj] = rA[mh][jj] * 64;
      ldsB[mh][jj] = rB[mh][jj] * 64;
    }

  const int NT = K >> 6;   // K-tiles of 64

#define SG_A(buf, t, mh)                                                \
  do {                                                                  \
    gload16(gAp[mh][0] + (t) * 64, &sA[buf][ldsA[mh][0]]);              \
    gload16(gAp[mh][1] + (t) * 64, &sA[buf][ldsA[mh][1]]);              \
  } while (0)
#define SG_B(buf, t, nh)                                                \
  do {                                                                  \
    gload16(gBp[nh][0] + (t) * 64, &sB[buf][ldsB[nh][0]]);              \
    gload16(gBp[nh][1] + (t) * 64, &sB[buf][ldsB[nh][1]]);              \
  } while (0)

  // prologue: T0 fully, then T1.A0, T1.B0 (FIFO order matters)
  SG_A(0, 0, 0); SG_B(0, 0, 0); SG_A(0, 0, 1); SG_B(0, 0, 1);
  SG_A(1, 1, 0); SG_B(1, 1, 0);
  sfence(); wait_vm4(); sfence();
  rbar();

  for (int t = 0; t < NT; ++t) {
    const int cur = t & 1;
    const int nxt = cur ^ 1;
    const unsigned short* aS = &sA[cur][0];
    const unsigned short* bS = &sB[cur][0];

#define PHASE(mh, nh, STG, BOUND)                                            \
    do {                                                                     \
      bf16x8 afr[4][2], bfr[2][2];                                           \
      _Pragma("unroll")                                                      \
      for (int ks = 0; ks < 2; ++ks) {                                       \
        _Pragma("unroll")                                                    \
        for (int nf = 0; nf < 2; ++nf) {                                     \
          const int r = wn + (nh) * 32 + nf * 16 + lr;                       \
          bfr[nf][ks] = *(const bf16x8*)(bS + r * 64 +                       \
                          (((ks * 4 + quad) ^ (r & 7)) * 8));                \
        }                                                                    \
        _Pragma("unroll")                                                    \
        for (int m = 0; m < 4; ++m) {                                        \
          const int r = wm + (mh) * 64 + m * 16 + lr;                        \
          afr[m][ks] = *(const bf16x8*)(aS + r * 64 +                        \
                          (((ks * 4 + quad) ^ (r & 7)) * 8));                \
        }                                                                    \
      }                                                                      \
      STG;                                                                   \
      __builtin_amdgcn_s_setprio(1);                                         \
      _Pragma("unroll")                                                      \
      for (int m = 0; m < 4; ++m)                                            \
        _Pragma("unroll")                                                    \
        for (int nf = 0; nf < 2; ++nf)                                       \
          _Pragma("unroll")                                                  \
          for (int ks = 0; ks < 2; ++ks)                                     \
            acc[(mh) * 4 + m][(nh) * 2 + nf] =                               \
                __builtin_amdgcn_mfma_f32_16x16x32_bf16(                     \
                    afr[m][ks], bfr[nf][ks],                                 \
                    acc[(mh) * 4 + m][(nh) * 2 + nf], 0, 0, 0);              \
      __builtin_amdgcn_s_setprio(0);                                         \
      if (BOUND) {                                                           \
        sfence();                                                            \
        if (t + 2 < NT) wait_vm4(); else wait_vm0();                         \
        sfence();                                                            \
      }                                                                      \
      rbar();                                                                \
    } while (0)

    PHASE(0, 0, if (t + 1 < NT) SG_A(nxt, t + 1, 1), false);
    PHASE(0, 1, if (t + 1 < NT) SG_B(nxt, t + 1, 1), false);
    PHASE(1, 0, if (t + 2 < NT) SG_A(cur, t + 2, 0), false);
    PHASE(1, 1, if (t + 2 < NT) SG_B(cur, t + 2, 0), (t + 1 < NT));
#undef PHASE
  }
#undef SG_A
#undef SG_B

  if (MODE == 0) {
    if (n0 < 2048) {
      const float qs = (n0 < 1024) ? 0.18033688011112042f : 1.0f;
#pragma unroll
      for (int m = 0; m < 8; ++m) {
        const int row = m0 + wm + m * 16 + quad * 4;
#pragma unroll
        for (int nf = 0; nf < 4; ++nf) {
          const int col = n0 + wn + nf * 16 + lr;
#pragma unroll
          for (int r = 0; r < 4; ++r)
            qk[(long)(row + r) * 2048 + col] = f2bf(acc[m][nf][r] * qs);
        }
      }
    } else {
#pragma unroll
      for (int m = 0; m < 8; ++m) {
        const int tok = m0 + wm + m * 16 + quad * 4;
        const int bb  = tok >> 11, tt = tok & 2047;
#pragma unroll
        for (int nf = 0; nf < 4; ++nf) {
          const int fv = n0 - 2048 + wn + nf * 16 + lr;  // h*64+d
          ushort4 p;
          p.x = f2bf(acc[m][nf][0]); p.y = f2bf(acc[m][nf][1]);
          p.z = f2bf(acc[m][nf][2]); p.w = f2bf(acc[m][nf][3]);
          *(ushort4*)(vT + ((long)(bb * 1024 + fv)) * 2048 + tt) = p;
        }
      }
    }
  } else {
#pragma unroll
    for (int m = 0; m < 8; ++m) {
      const int row = m0 + wm + m * 16 + quad * 4;
#pragma unroll
      for (int nf = 0; nf < 4; ++nf) {
        const int col = n0 + wn + nf * 16 + lr;
#pragma unroll
        for (int r = 0; r < 4; ++r)
          outp[(long)(row + r) * 1024 + col] = acc[m][nf][r];
      }
    }
  }
}

// ---------------- flash attention (unchanged from r2) -----------------------
__global__ __launch_bounds__(256, 4)
void attn_kernel(const unsigned short* __restrict__ qk,
                 const unsigned short* __restrict__ vT,
                 unsigned short* __restrict__ attnb) {
  __shared__ unsigned short sK[2][64 * 64];
  __shared__ unsigned short sV[2][64 * 64];
  const int tid = threadIdx.x;
  const int w   = tid >> 6;
  const int l   = tid & 63;
  const int l31 = l & 31;
  const int lh  = l >> 5;
  const int h8  = lh * 8;
  const int bh  = blockIdx.x;
  const int hh  = bh & 15;
  const long tokbase = (long)(bh >> 4) * TB;
  const int qbase = blockIdx.y * 128 + w * 32;

  bf16x8 qf[4];
  {
    const unsigned short* qptr = qk + (tokbase + qbase + l31) * 2048 + hh * 64 + h8;
#pragma unroll
    for (int s = 0; s < 4; ++s) qf[s] = *(const bf16x8*)(qptr + s * 16);
  }

  const int srow = l >> 3;
  const int g    = (l & 7) ^ srow;
  const unsigned short* kbase =
      qk + (tokbase + w * 16 + srow) * 2048 + 1024 + hh * 64 + g * 8;
  const unsigned short* vbase =
      vT + ((long)bh * 64 + w * 16 + srow) * 2048 + g * 8;

  f32x16 oacc[2] = {{}, {}};
  f32x2 lp2 = {0.f, 0.f};

  gload16(kbase,            &sK[0][(w * 16 + 0) * 64]);
  gload16(kbase + 8 * 2048, &sK[0][(w * 16 + 8) * 64]);
  gload16(vbase,            &sV[0][(w * 16 + 0) * 64]);
  gload16(vbase + 8 * 2048, &sV[0][(w * 16 + 8) * 64]);

  for (int t = 0; t < 32; ++t) {
    const int buf = t & 1;
    if (t + 1 < 32) {
      const int k0 = (t + 1) * 64;
      const int nb = buf ^ 1;
      gload16(kbase + (long)k0 * 2048,            &sK[nb][(w * 16 + 0) * 64]);
      gload16(kbase + (long)k0 * 2048 + 8 * 2048, &sK[nb][(w * 16 + 8) * 64]);
      gload16(vbase + k0,                         &sV[nb][(w * 16 + 0) * 64]);
      gload16(vbase + k0 + 8 * 2048,              &sV[nb][(w * 16 + 8) * 64]);
      wait_vm4();
    } else {
      wait_vm0();
    }
    sfence();
    rbar();
    sfence();
    const unsigned short* bK = sK[buf];
    const unsigned short* bV = sV[buf];

#pragma unroll
    for (int G = 0; G < 2; ++G) {
      f32x16 sacc = {};
      __builtin_amdgcn_s_setprio(1);
#pragma unroll
      for (int s = 0; s < 4; ++s) {
        const int key = G * 32 + l31;
        const int p   = (s * 2 + lh) ^ (key & 7);
        const bf16x8 kf = *(const bf16x8*)(bK + key * 64 + p * 8);
        sacc = __builtin_amdgcn_mfma_f32_32x32x16_bf16(kf, qf[s], sacc, 0, 0, 0);
      }
      __builtin_amdgcn_s_setprio(0);
      float e[16];
#pragma unroll
      for (int i = 0; i < 16; ++i) e[i] = __builtin_amdgcn_exp2f(sacc[i]);
#pragma unroll
      for (int i = 0; i < 8; ++i) {
        f32x2 pr = {e[2 * i], e[2 * i + 1]};
        lp2 += pr;
      }
      unsigned d[8];
#pragma unroll
      for (int i = 0; i < 8; ++i) d[i] = pack2bf(e[2 * i], e[2 * i + 1]);
      plswap(d[0], d[2]); plswap(d[1], d[3]);
      plswap(d[4], d[6]); plswap(d[5], d[7]);
      bf16x8 pp[2];
      pp[0] = frag4(d[0], d[1], d[2], d[3]);
      pp[1] = frag4(d[4], d[5], d[6], d[7]);
      __builtin_amdgcn_s_setprio(1);
#pragma unroll
      for (int sub = 0; sub < 2; ++sub) {
        const int gt  = (G * 2 + sub) * 2 + lh;
        const int d0r = l31, d1r = 32 + l31;
        const bf16x8 vf0 = *(const bf16x8*)(bV + d0r * 64 + ((gt ^ (d0r & 7))) * 8);
        const bf16x8 vf1 = *(const bf16x8*)(bV + d1r * 64 + ((gt ^ (d1r & 7))) * 8);
        oacc[0] = __builtin_amdgcn_mfma_f32_32x32x16_bf16(pp[sub], vf0, oacc[0], 0, 0, 0);
        oacc[1] = __builtin_amdgcn_mfma_f32_32x32x16_bf16(pp[sub], vf1, oacc[1], 0, 0, 0);
      }
      __builtin_amdgcn_s_setprio(0);
    }
    sfence();
    rbar();
  }

  const float lp = lp2.x + lp2.y;
  const float fs = lp + __shfl_xor(lp, 32);
  const float rc = 1.0f / fs;
#pragma unroll
  for (int r = 0; r < 16; ++r) {
    const int row = (r & 3) + 8 * (r >> 2) + 4 * lh;
    const float sc = __shfl(rc, row);
    const long base = (tokbase + qbase + row) * 1024 + hh * 64;
    attnb[base + l31]      = f2bf(oacc[0][r] * sc);
    attnb[base + 32 + l31] = f2bf(oacc[1][r] * sc);
  }
}

// ---------------------------------------------------------------------------
extern "C" void kernel_launch(void* const* d_in, const int* in_sizes, int n_in,
                              void* d_out, int out_size, void* d_ws, size_t ws_size,
                              hipStream_t stream) {
  const float* x    = (const float*)d_in[0];
  const float* wqkv = (const float*)d_in[1];
  const float* wout = (const float*)d_in[2];
  float* outp = (float*)d_out;

  unsigned short* xb    = (unsigned short*)d_ws;          // 8192*1024
  unsigned short* wqkvb = xb    + (long)NTOK * EMB;       // 3072*1024
  unsigned short* woutb = wqkvb + (long)FQKV * EMB;       // 1024*1024
  unsigned short* qkb   = woutb + (long)EMB * EMB;        // 8192*2048 (Q|K)
  unsigned short* vTb   = qkb   + (long)NTOK * 2048;      // 4*16*64*2048
  unsigned short* attnb = vTb   + (long)4 * 16 * 64 * TB; // 8192*1024

  cvt_kernel<<<12288, 256, 0, stream>>>(
      (const float4*)x, (const float4*)wqkv, (const float4*)wout,
      (ushort4*)xb, (ushort4*)wqkvb, (ushort4*)woutb);

  // QKV projection: 256^2 8-phase GEMM (12 x 32 = 384 blocks)
  gemm8p<0><<<dim3(12, 32), 512, 0, stream>>>(xb, wqkvb, EMB, qkb, vTb, nullptr);

  attn_kernel<<<dim3(64, 16), 256, 0, stream>>>(qkb, vTb, attnb);

  // output projection: same 8-phase kernel (4 x 32 = 128 blocks)
  gemm8p<1><<<dim3(4, 32), 512, 0, stream>>>(attnb, woutb, EMB, nullptr, nullptr, outp);
}